// Round 4
// baseline (350.214 us; speedup 1.0000x reference)
//
#include <hip/hip_runtime.h>
#include <stdint.h>

// ---------------------------------------------------------------------------
// LongSelfAttention: x[16384,1024] -> QKV proj -> per-token 16x16 head attn
// -> O proj. GEMMs: bf16 MFMA 16x16x32, 128x128 tile, BK=64 (two 32-K slabs
// per barrier pair), global_load_lds w=16, XCD-swizzled 1D grid. QKV split
// into two launches for profiler visibility. Attention: MFMA scores +
// shuffle softmax + MFMA PV.
// Workspace layout (bytes):
//   [0,            32 MiB) x_bf16           [16384][1024]
//   [32 MiB,       40 MiB) W^T bf16 x4      [4][1024][1024]  (q,k,v,o)
//   [40 MiB,      136 MiB) qkv bf16         [3][16384][1024]  (attn overwrites q)
// ---------------------------------------------------------------------------

typedef __attribute__((ext_vector_type(8))) short short8;
typedef __attribute__((ext_vector_type(4))) float floatx4;
typedef __attribute__((address_space(1))) unsigned int gu32;
typedef __attribute__((address_space(3))) unsigned int lu32;

#define HID 1024
#define MTOK 16384                 // B*L
#define WELEM (HID * HID)          // 1048576
#define XELEM (MTOK * HID)         // 16777216

__device__ __forceinline__ unsigned short f2bf(float f) {
  union { float f; uint32_t u; } v; v.f = f;
  uint32_t u = v.u;
  u += 0x7fffu + ((u >> 16) & 1u);   // round-to-nearest-even
  return (unsigned short)(u >> 16);
}

// ---- x fp32 -> bf16, vectorized -------------------------------------------
__global__ __launch_bounds__(256) void cvt_x_kernel(const float* __restrict__ x,
                                                    unsigned short* __restrict__ xb) {
  const int idx = blockIdx.x * 256 + threadIdx.x;
  float4 v = ((const float4*)x)[idx];
  ushort4 o;
  o.x = f2bf(v.x); o.y = f2bf(v.y); o.z = f2bf(v.z); o.w = f2bf(v.w);
  ((ushort4*)xb)[idx] = o;
}

// ---- W [k][n] fp32 -> W^T [n][k] bf16 via 64x64 LDS tile ------------------
__global__ __launch_bounds__(256) void cvt_w_kernel(const float* __restrict__ W0,
                                                    const float* __restrict__ W1,
                                                    const float* __restrict__ W2,
                                                    const float* __restrict__ W3,
                                                    unsigned short* __restrict__ WT) {
  const float* W = (blockIdx.z == 0) ? W0 : (blockIdx.z == 1) ? W1
                   : (blockIdx.z == 2) ? W2 : W3;
  unsigned short* out = WT + (size_t)blockIdx.z * WELEM;
  __shared__ float tile[64][65];
  const int t = threadIdx.x;
  const int n0 = blockIdx.x * 64, k0 = blockIdx.y * 64;
#pragma unroll
  for (int i = 0; i < 4; i++) {
    const int row = i * 16 + (t >> 4);     // k within tile
    const int col = (t & 15) * 4;          // n within tile
    float4 v = *(const float4*)&W[(size_t)(k0 + row) * HID + n0 + col];
    tile[row][col] = v.x; tile[row][col + 1] = v.y;
    tile[row][col + 2] = v.z; tile[row][col + 3] = v.w;
  }
  __syncthreads();
#pragma unroll
  for (int i = 0; i < 4; i++) {
    const int n = i * 16 + (t >> 4);
    const int k = (t & 15) * 4;
    ushort4 o;
    o.x = f2bf(tile[k][n]);     o.y = f2bf(tile[k + 1][n]);
    o.z = f2bf(tile[k + 2][n]); o.w = f2bf(tile[k + 3][n]);
    *(ushort4*)&out[(size_t)(n0 + n) * HID + k0 + k] = o;
  }
}

// ---- NT GEMM core: C[m,n] = A[m,:].BT[n,:] + bias[n] ----------------------
// 128x128 tile, BK=64 as two 32-K slabs (per-slab layout identical to the
// verified BK=32 pattern), 4 waves, wave does 64x64 via 4x4 MFMAs per slab.
// QKV=true: grid 1536 x2 launches (m-halves via mbase), bf16 out to qkv[z].
// QKV=false: grid 1024, fp32 out.
template <bool QKV>
__global__ __launch_bounds__(256) void gemm_bt1d(
    const unsigned short* __restrict__ A,     // [MTOK][HID] bf16
    const unsigned short* __restrict__ BTb,   // base of W^T array
    const float* __restrict__ b0, const float* __restrict__ b1,
    const float* __restrict__ b2,
    void* __restrict__ Cv, int mbase)
{
  const int i = blockIdx.x;
  const int xcd = i & 7;
  const int j = i >> 3;
  int mb, nb;
  if constexpr (QKV) {
    nb = j >> 3;                             // 0..23 (n outer)
    mb = mbase + xcd * 8 + (j & 7);          // XCD m-band of 8
  } else {
    const int round = j >> 5;                // 4 rounds of 32 m-blocks
    const int jj = j & 31;
    nb = jj >> 2;                            // 0..7
    mb = xcd * 4 + round * 32 + (jj & 3);    // band of 4
  }
  const int z = QKV ? (nb >> 3) : 0;
  const int n0 = QKV ? ((nb & 7) * 128) : (nb * 128);
  const int m0 = mb * 128;
  const unsigned short* BT = BTb + (size_t)(QKV ? z : 3) * WELEM;
  const float* bias = QKV ? ((z == 0) ? b0 : ((z == 1) ? b1 : b2)) : b0;

  __shared__ unsigned short Als[2][128 * 32];   // [k-slab][row*32]
  __shared__ unsigned short Bls[2][128 * 32];

  const int t = threadIdx.x;
  const int wv = t >> 6;
  const int lane = t & 63;
  const int quad = lane >> 4;
  const int r16 = lane & 15;
  const int wr = wv >> 1, wc = wv & 1;

  floatx4 acc[4][4] = {};

  const int srow = t >> 2;
  const int scol = (t & 3) * 8;
  const unsigned short* Ag = A + (size_t)(m0 + srow) * HID + scol;
  const unsigned short* Bg = BT + (size_t)(n0 + srow) * HID + scol;
  const int wbase = (wv * 16) * 32;            // wave-uniform LDS base

  for (int ko = 0; ko < HID; ko += 64) {
#pragma unroll
    for (int s = 0; s < 2; s++) {
      const int kk = ko + s * 32;
      __builtin_amdgcn_global_load_lds((const gu32*)(Ag + kk),            (lu32*)(Als[s] + wbase),           16, 0, 0);
      __builtin_amdgcn_global_load_lds((const gu32*)(Ag + 64 * HID + kk), (lu32*)(Als[s] + wbase + 64 * 32), 16, 0, 0);
      __builtin_amdgcn_global_load_lds((const gu32*)(Bg + kk),            (lu32*)(Bls[s] + wbase),           16, 0, 0);
      __builtin_amdgcn_global_load_lds((const gu32*)(Bg + 64 * HID + kk), (lu32*)(Bls[s] + wbase + 64 * 32), 16, 0, 0);
    }
    __syncthreads();

#pragma unroll
    for (int s = 0; s < 2; s++) {
      short8 a[4], b[4];
#pragma unroll
      for (int ii = 0; ii < 4; ii++)
        a[ii] = *(const short8*)(Als[s] + (wr * 64 + ii * 16 + r16) * 32 + quad * 8);
#pragma unroll
      for (int jj = 0; jj < 4; jj++)
        b[jj] = *(const short8*)(Bls[s] + (wc * 64 + jj * 16 + r16) * 32 + quad * 8);
#pragma unroll
      for (int ii = 0; ii < 4; ii++)
#pragma unroll
        for (int jj = 0; jj < 4; jj++)
          acc[ii][jj] = __builtin_amdgcn_mfma_f32_16x16x32_bf16(a[ii], b[jj], acc[ii][jj], 0, 0, 0);
    }
    __syncthreads();
  }

  // epilogue: C/D layout col=lane&15, row=quad*4+reg (measured m89/m91)
#pragma unroll
  for (int jj = 0; jj < 4; jj++) {
    const int col = n0 + wc * 64 + jj * 16 + r16;
    const float bb = bias[col];
#pragma unroll
    for (int ii = 0; ii < 4; ii++) {
      const int row0 = m0 + wr * 64 + ii * 16 + quad * 4;
#pragma unroll
      for (int rr = 0; rr < 4; rr++) {
        const float val = acc[ii][jj][rr] + bb;
        if constexpr (QKV)
          ((unsigned short*)Cv)[(size_t)z * XELEM + (size_t)(row0 + rr) * HID + col] = f2bf(val);
        else
          ((float*)Cv)[(size_t)(row0 + rr) * HID + col] = val;
      }
    }
  }
}

// ---- per-token head attention: one wave per token, all-MFMA ---------------
__global__ __launch_bounds__(256) void attn_kernel(const unsigned short* qkv,
                                                   unsigned short* attn) {
  __shared__ unsigned short vls[4][1056];    // per wave: rows0-7 @0, rows8-15 @528
  __shared__ unsigned short pls[4][16 * 24]; // P bf16, stride 24 ushorts (48B)

  const int t = threadIdx.x;
  const int wv = t >> 6, lane = t & 63;
  const int quad = lane >> 4, r16 = lane & 15;
  const size_t base = ((size_t)blockIdx.x * 4 + wv) * HID;
  const unsigned short* qp = qkv + base;                     // q[16][64]
  const unsigned short* kp = qkv + (size_t)XELEM + base;     // k[16][64]
  const unsigned short* vp = qkv + 2 * (size_t)XELEM + base; // v[16][64]

  // V -> LDS (bf16, no conversion), 16B/lane DMA
  __builtin_amdgcn_global_load_lds((const gu32*)(vp + lane * 8),       (lu32*)&vls[wv][0],   16, 0, 0);
  __builtin_amdgcn_global_load_lds((const gu32*)(vp + 512 + lane * 8), (lu32*)&vls[wv][528], 16, 0, 0);

  // q/k A/B fragments direct from global (verified m97-pattern layout)
  short8 qf0 = *(const short8*)(qp + r16 * 64 + quad * 8);
  short8 qf1 = *(const short8*)(qp + r16 * 64 + quad * 8 + 32);
  short8 kf0 = *(const short8*)(kp + r16 * 64 + quad * 8);
  short8 kf1 = *(const short8*)(kp + r16 * 64 + quad * 8 + 32);

  // scores = q.k^T / 8 (fp32 accum in MFMA)
  floatx4 sc = {0.f, 0.f, 0.f, 0.f};
  sc = __builtin_amdgcn_mfma_f32_16x16x32_bf16(qf0, kf0, sc, 0, 0, 0);
  sc = __builtin_amdgcn_mfma_f32_16x16x32_bf16(qf1, kf1, sc, 0, 0, 0);

  // softmax over e (across 16 lanes of each quad), write P bf16 to LDS
#pragma unroll
  for (int rr = 0; rr < 4; rr++) {
    float s = sc[rr] * 0.125f;
    float m = s;
#pragma unroll
    for (int off = 1; off < 16; off <<= 1) m = fmaxf(m, __shfl_xor(m, off));
    float ex = __expf(s - m);
    float sum = ex;
#pragma unroll
    for (int off = 1; off < 16; off <<= 1) sum += __shfl_xor(sum, off);
    pls[wv][(quad * 4 + rr) * 24 + r16] = f2bf(ex / sum);   // P[h][e]
  }

  __syncthreads();   // covers V DMA completion + cross-lane P visibility

  // A-frag: P[m=r16][k=quad*8+j] (quads 0,1 real; 2,3 zero)
  const short8 zero8 = {0, 0, 0, 0, 0, 0, 0, 0};
  short8 af = zero8;
  short8 bf[4] = {zero8, zero8, zero8, zero8};
  if (quad < 2) {
    af = *(const short8*)&pls[wv][r16 * 24 + quad * 8];
#pragma unroll
    for (int c = 0; c < 4; c++)
#pragma unroll
      for (int jj = 0; jj < 8; jj++)
        bf[c][jj] = (short)vls[wv][quad * 528 + jj * 64 + c * 16 + r16];
  }

  floatx4 ov[4];
#pragma unroll
  for (int c = 0; c < 4; c++) {
    floatx4 z = {0.f, 0.f, 0.f, 0.f};
    ov[c] = __builtin_amdgcn_mfma_f32_16x16x32_bf16(af, bf[c], z, 0, 0, 0);
  }

  // C-layout: out[h=quad*4+rr][d=c*16+r16]; store bf16 (overwrites q: safe)
#pragma unroll
  for (int rr = 0; rr < 4; rr++)
#pragma unroll
    for (int c = 0; c < 4; c++)
      attn[base + (size_t)(quad * 4 + rr) * 64 + c * 16 + r16] = f2bf(ov[c][rr]);
}

extern "C" void kernel_launch(void* const* d_in, const int* in_sizes, int n_in,
                              void* d_out, int out_size, void* d_ws, size_t ws_size,
                              hipStream_t stream) {
  const float* x  = (const float*)d_in[0];
  const float* Wq = (const float*)d_in[1];
  const float* bq = (const float*)d_in[2];
  const float* Wk = (const float*)d_in[3];
  const float* bk = (const float*)d_in[4];
  const float* Wv = (const float*)d_in[5];
  const float* bv = (const float*)d_in[6];
  const float* Wo = (const float*)d_in[7];
  const float* bo = (const float*)d_in[8];

  char* ws = (char*)d_ws;
  unsigned short* xb  = (unsigned short*)ws;                        // 32 MiB
  unsigned short* wt  = (unsigned short*)(ws + (size_t)XELEM * 2);  // 8 MiB
  unsigned short* qkv = wt + 4 * (size_t)WELEM;                     // 96 MiB

  cvt_x_kernel<<<XELEM / 1024, 256, 0, stream>>>(x, xb);
  cvt_w_kernel<<<dim3(16, 16, 4), 256, 0, stream>>>(Wq, Wk, Wv, Wo, wt);
  gemm_bt1d<true><<<1536, 256, 0, stream>>>(xb, wt, bq, bk, bv, (void*)qkv, 0);
  gemm_bt1d<true><<<1536, 256, 0, stream>>>(xb, wt, bq, bk, bv, (void*)qkv, 64);
  attn_kernel<<<4096, 256, 0, stream>>>(qkv, qkv);  // attn overwrites q region
  gemm_bt1d<false><<<1024, 256, 0, stream>>>(qkv, wt, bo, bo, bo, d_out, 0);
}